// Round 9
// baseline (164.332 us; speedup 1.0000x reference)
//
#include <hip/hip_runtime.h>
#include <math.h>

typedef __bf16 bf16x8 __attribute__((ext_vector_type(8)));
typedef float  f32x4  __attribute__((ext_vector_type(4)));

constexpr int B_=2, S_=512, D_=512, H_=8, HD_=64, FFN_=2048, NC_=8;
constexpr float EPS_=1e-6f;

__device__ __forceinline__ __bf16 f2bf(float f){
    union{float f;unsigned u;}x; x.f=f;
    unsigned r=(x.u+0x7fffu+((x.u>>16)&1u))>>16;
    union{unsigned short s;__bf16 b;}y; y.s=(unsigned short)r; return y.b;
}
__device__ __forceinline__ float bf2f(unsigned short s){
    union{unsigned u;float f;}x; x.u=((unsigned)s)<<16; return x.f;
}
__device__ __forceinline__ void bf8_f32(uint4 p, float* o){
    unsigned w[4]={p.x,p.y,p.z,p.w};
#pragma unroll
    for(int i=0;i<4;i++){ o[2*i]=bf2f((unsigned short)(w[i]&0xffffu)); o[2*i+1]=bf2f((unsigned short)(w[i]>>16)); }
}
__device__ __forceinline__ f32x4 MF(bf16x8 a, bf16x8 b, f32x4 c){
    return __builtin_amdgcn_mfma_f32_16x16x32_bf16(a,b,c,0,0,0);
}
#define GLOAD16(g,l) __builtin_amdgcn_global_load_lds((__attribute__((address_space(1))) const void*)(g),(__attribute__((address_space(3))) void*)(l),16,0,0)

__device__ __forceinline__ void rowsq_atomic(float* accb, int row0, int lane, float p[4]){
#pragma unroll
    for(int r=0;r<4;r++){
        float v = p[r];
        v += __shfl_xor(v, 1, 64);
        v += __shfl_xor(v, 2, 64);
        v += __shfl_xor(v, 4, 64);
        v += __shfl_xor(v, 8, 64);
        if((lane&15)==0) atomicAdd(accb + row0 + r, v);
    }
}

// ---------------- prep: weight transpose+cvt, rs1, zero accumulators --------
__global__ __launch_bounds__(256) void prep_k(const float* __restrict__ Wg,
    const float* __restrict__ Wu, const float* __restrict__ Wd,
    const float* __restrict__ Wq, const float* __restrict__ Wk,
    const float* __restrict__ Wv, const float* __restrict__ Wo,
    __bf16* __restrict__ WT, const float* __restrict__ inputs,
    float* __restrict__ rs1, float* __restrict__ rs2acc, float* __restrict__ rs3acc){
    __shared__ __bf16 s[64][72];
    int t = blockIdx.x, tid = threadIdx.x;
    if(t >= 1024){
        int row = (t-1024)*4 + (tid>>6), lane = tid&63;
        const float4* p = (const float4*)(inputs + (size_t)row*D_) + lane*2;
        float4 a=p[0], b=p[1];
        float ss = a.x*a.x+a.y*a.y+a.z*a.z+a.w*a.w + b.x*b.x+b.y*b.y+b.z*b.z+b.w*b.w;
        for(int off=32; off>0; off>>=1) ss += __shfl_down(ss, off, 64);
        if(lane==0) rs1[row] = rsqrtf(ss/(float)D_ + EPS_);
        float4 z = {0.f,0.f,0.f,0.f};
        if(t==1024) ((float4*)rs2acc)[tid] = z;
        if(t==1025) ((float4*)rs3acc)[tid] = z;
        return;
    }
    const float* src; __bf16* dst; int K,N,lt;
    if      (t<256){ src=Wg; dst=WT;          K=512;  N=2048; lt=t; }
    else if (t<512){ src=Wu; dst=WT+1048576;  K=512;  N=2048; lt=t-256; }
    else if (t<768){ src=Wd; dst=WT+2097152;  K=2048; N=512;  lt=t-512; }
    else if (t<832){ src=Wq; dst=WT+3145728;  K=512;  N=512;  lt=t-768; }
    else if (t<896){ src=Wk; dst=WT+3407872;  K=512;  N=512;  lt=t-832; }
    else if (t<960){ src=Wv; dst=WT+3670016;  K=512;  N=512;  lt=t-896; }
    else           { src=Wo; dst=WT+3932160;  K=512;  N=512;  lt=t-960; }
    int nt64 = N>>6, tk = lt/nt64, tn = lt%nt64;
    {
        int jk = tid>>2, jn0 = (tid&3)*16;
        const float* p = src + (size_t)(tk*64+jk)*N + tn*64 + jn0;
        float4 a0=((const float4*)p)[0], a1=((const float4*)p)[1],
               a2=((const float4*)p)[2], a3=((const float4*)p)[3];
        bf16x8 w0, w1;
        w0[0]=f2bf(a0.x); w0[1]=f2bf(a0.y); w0[2]=f2bf(a0.z); w0[3]=f2bf(a0.w);
        w0[4]=f2bf(a1.x); w0[5]=f2bf(a1.y); w0[6]=f2bf(a1.z); w0[7]=f2bf(a1.w);
        w1[0]=f2bf(a2.x); w1[1]=f2bf(a2.y); w1[2]=f2bf(a2.z); w1[3]=f2bf(a2.w);
        w1[4]=f2bf(a3.x); w1[5]=f2bf(a3.y); w1[6]=f2bf(a3.z); w1[7]=f2bf(a3.w);
        *(bf16x8*)&s[jk][jn0] = w0; *(bf16x8*)&s[jk][jn0+8] = w1;
    }
    __syncthreads();
    {
        int jn = tid&63, jkq = (tid>>6)*16;
        bf16x8 w0, w1;
#pragma unroll
        for(int j=0;j<8;j++){ w0[j]=s[jkq+j][jn]; w1[j]=s[jkq+8+j][jn]; }
        __bf16* q = dst + (size_t)(tn*64+jn)*K + tk*64 + jkq;
        *(bf16x8*)q = w0; *(bf16x8*)(q+8) = w1;
    }
}

// ---------------- staging helpers (64x64 tiles, BK=64) ----------------------
__device__ __forceinline__ void stageB1(const __bf16* __restrict__ Bt, int n0, int K, int kk,
                                        __bf16* sB0, __bf16* sB1, int wave, int lane){
    int row = (wave<<4) + (lane>>2), kq = (lane&3)<<3;
    const __bf16* g = Bt + (size_t)(n0+row)*K + kk + kq;
    GLOAD16(g,      sB0 + (wave<<9));
    GLOAD16(g + 32, sB1 + (wave<<9));
}
struct ARf { float4 a0,a1,a2,a3, g0,g1,g2,g3; };
__device__ __forceinline__ ARf loadA_f32(const float* __restrict__ A, const float* __restrict__ g,
                                         int m0, int K, int kk, int tid){
    int row = tid>>2, kq = (tid&3)<<4;
    const float4* p = (const float4*)(A + (size_t)(m0+row)*K + kk + kq);
    const float4* gp = (const float4*)(g + kk + kq);
    ARf o;
    o.a0=p[0]; o.a1=p[1]; o.a2=p[2]; o.a3=p[3];
    o.g0=gp[0]; o.g1=gp[1]; o.g2=gp[2]; o.g3=gp[3];
    return o;
}
__device__ __forceinline__ void writeA_f32(const ARf& o, float r, __bf16* sA0, __bf16* sA1, int tid){
    int row = tid>>2, kq = (tid&3)<<4;
    bf16x8 w0, w1;
    w0[0]=f2bf(o.a0.x*r*o.g0.x); w0[1]=f2bf(o.a0.y*r*o.g0.y);
    w0[2]=f2bf(o.a0.z*r*o.g0.z); w0[3]=f2bf(o.a0.w*r*o.g0.w);
    w0[4]=f2bf(o.a1.x*r*o.g1.x); w0[5]=f2bf(o.a1.y*r*o.g1.y);
    w0[6]=f2bf(o.a1.z*r*o.g1.z); w0[7]=f2bf(o.a1.w*r*o.g1.w);
    w1[0]=f2bf(o.a2.x*r*o.g2.x); w1[1]=f2bf(o.a2.y*r*o.g2.y);
    w1[2]=f2bf(o.a2.z*r*o.g2.z); w1[3]=f2bf(o.a2.w*r*o.g2.w);
    w1[4]=f2bf(o.a3.x*r*o.g3.x); w1[5]=f2bf(o.a3.y*r*o.g3.y);
    w1[6]=f2bf(o.a3.z*r*o.g3.z); w1[7]=f2bf(o.a3.w*r*o.g3.w);
    __bf16* d = (kq<32) ? (sA0 + row*32 + kq) : (sA1 + row*32 + kq-32);
    *(bf16x8*)d = w0; *(bf16x8*)(d+8) = w1;
}
struct ARb { uint4 p0,p1; float4 g0,g1,g2,g3; };
__device__ __forceinline__ ARb loadA_bf16(const __bf16* __restrict__ A, const float* __restrict__ g,
                                          int m0, int K, int kk, int tid){
    int row = tid>>2, kq = (tid&3)<<4;
    const __bf16* p = A + (size_t)(m0+row)*K + kk + kq;
    const float4* gp = (const float4*)(g + kk + kq);
    ARb o;
    o.p0 = *(const uint4*)p; o.p1 = *(const uint4*)(p+8);
    o.g0=gp[0]; o.g1=gp[1]; o.g2=gp[2]; o.g3=gp[3];
    return o;
}
__device__ __forceinline__ void writeA_bf16(const ARb& o, float r, __bf16* sA0, __bf16* sA1, int tid){
    int row = tid>>2, kq = (tid&3)<<4;
    float v[16]; bf8_f32(o.p0, v); bf8_f32(o.p1, v+8);
    float gf[16] = {o.g0.x,o.g0.y,o.g0.z,o.g0.w, o.g1.x,o.g1.y,o.g1.z,o.g1.w,
                    o.g2.x,o.g2.y,o.g2.z,o.g2.w, o.g3.x,o.g3.y,o.g3.z,o.g3.w};
    bf16x8 w0, w1;
#pragma unroll
    for(int j=0;j<8;j++){ w0[j]=f2bf(v[j]*r*gf[j]); w1[j]=f2bf(v[8+j]*r*gf[8+j]); }
    __bf16* d = (kq<32) ? (sA0 + row*32 + kq) : (sA1 + row*32 + kq-32);
    *(bf16x8*)d = w0; *(bf16x8*)(d+8) = w1;
}
// A-stage for 32-row tiles (8 elems/thread), bf16 input + fused RMS
struct AR32 { uint4 p0; float4 g0,g1; };
__device__ __forceinline__ AR32 loadA32(const __bf16* __restrict__ A, const float* __restrict__ g,
                                        int m0, int K, int kk, int tid){
    int row = tid>>3, kq = (tid&7)*8;
    AR32 o;
    o.p0 = *(const uint4*)(A + (size_t)(m0+row)*K + kk + kq);
    const float4* gp = (const float4*)(g + kk + kq);
    o.g0 = gp[0]; o.g1 = gp[1];
    return o;
}
__device__ __forceinline__ void writeA32(const AR32& o, float r, __bf16* sA0, __bf16* sA1, int tid){
    int row = tid>>3, kq = (tid&7)*8;
    float v[8]; bf8_f32(o.p0, v);
    float gf[8] = {o.g0.x,o.g0.y,o.g0.z,o.g0.w, o.g1.x,o.g1.y,o.g1.z,o.g1.w};
    bf16x8 w;
#pragma unroll
    for(int j=0;j<8;j++) w[j]=f2bf(v[j]*r*gf[j]);
    __bf16* d = (kq<32) ? (sA0 + row*32 + kq) : (sA1 + row*32 + kq-32);
    *(bf16x8*)d = w;
}
__device__ __forceinline__ void mfma_tile(const __bf16* sA0, const __bf16* sA1,
        const __bf16* sB0, const __bf16* sB1, int wave, int lane, f32x4 acc[4]){
    int ar = (((wave<<4)+(lane&15))<<5) + ((lane>>4)<<3);
    bf16x8 a0 = *(const bf16x8*)(sA0+ar);
    bf16x8 a1 = *(const bf16x8*)(sA1+ar);
#pragma unroll
    for(int nt=0;nt<4;nt++){
        int br = (((nt<<4)+(lane&15))<<5) + ((lane>>4)<<3);
        acc[nt] = MF(a0, *(const bf16x8*)(sB0+br), acc[nt]);
        acc[nt] = MF(a1, *(const bf16x8*)(sB1+br), acc[nt]);
    }
}

// ---------------- QKV fused GEMM (relu on q,k), pipelined, coalesced store --
__global__ __launch_bounds__(256) void gemm_qkv_k(const float* __restrict__ in,
        const float* __restrict__ rs1, const float* __restrict__ ln1,
        const __bf16* __restrict__ Bt, __bf16* __restrict__ Qb,
        __bf16* __restrict__ Kb, __bf16* __restrict__ Vb){
    __shared__ __bf16 sA0[2][2048], sA1[2][2048], sB0[2][2048], sB1[2][2048];
    int tid=threadIdx.x, wave=tid>>6, lane=tid&63;
    int n0 = blockIdx.x*64, m0 = blockIdx.y*64;
    float r = rs1[m0+(tid>>2)];
    f32x4 acc[4] = {};
    {
        ARf a = loadA_f32(in, ln1, m0, 512, 0, tid);
        stageB1(Bt, n0, 512, 0, sB0[0], sB1[0], wave, lane);
        writeA_f32(a, r, sA0[0], sA1[0], tid);
        __syncthreads();
    }
    int cur = 0;
#pragma unroll
    for(int it=0; it<8; ++it){
        int nxt = cur^1;
        ARf a;
        if(it<7){
            a = loadA_f32(in, ln1, m0, 512, (it+1)*64, tid);
            stageB1(Bt, n0, 512, (it+1)*64, sB0[nxt], sB1[nxt], wave, lane);
        }
        mfma_tile(sA0[cur],sA1[cur],sB0[cur],sB1[cur],wave,lane,acc);
        if(it<7) writeA_f32(a, r, sA0[nxt], sA1[nxt], tid);
        __syncthreads();
        cur = nxt;
    }
    int seg = n0>>9, nc = n0&511;
    __bf16* Out = seg==0 ? Qb : (seg==1 ? Kb : Vb);
    bool rl = seg<2;
    __bf16* tile = &sA0[0][0];
    int r0 = (wave<<4) + ((lane>>4)<<2);
#pragma unroll
    for(int nt=0;nt<4;nt++){
        int col = nt*16 + (lane&15);
#pragma unroll
        for(int rr=0;rr<4;rr++){
            float v = acc[nt][rr]; if(rl) v = fmaxf(v,0.f);
            tile[(r0+rr)*64 + col] = f2bf(v);
        }
    }
    __syncthreads();
#pragma unroll
    for(int p=0;p<2;p++){
        int row = (tid>>3) + p*32, c0 = (tid&7)*8;
        *(uint4*)(Out + (size_t)(m0+row)*512 + nc + c0) = *(const uint4*)&tile[row*64 + c0];
    }
}

// ---------------- scan A: M[i][j] = sum_t ssp[t] v[t][i] k[t][j] ------------
__global__ __launch_bounds__(256) void scanA_k(const __bf16* __restrict__ Kb,
        const __bf16* __restrict__ Vb, const float* __restrict__ mask,
        __bf16* __restrict__ MS, float* __restrict__ Pws){
    int bid = blockIdx.x;
    int c = bid&7, h = (bid>>3)&7, b = bid>>6;
    __shared__ __bf16 sKT[4096], sVT[4096];
    __shared__ float scv[64], ssp[64];
    int tid = threadIdx.x, wave = tid>>6, lane = tid&63;
    const __bf16* Kg = Kb + (size_t)(b*512 + c*64)*512 + h*64;
    const __bf16* Vg = Vb + (size_t)(b*512 + c*64)*512 + h*64;
    if(tid<64) scv[tid] = 1.f - mask[b*512 + c*64 + tid];
    __syncthreads();
    if(tid==0){
        float sp = 1.f;
        for(int t=63;t>=0;--t){ ssp[t]=sp; sp*=scv[t]; }
        Pws[bid] = sp;
    }
    __syncthreads();
#pragma unroll
    for(int p=0;p<2;p++){
        int t = (tid>>3) + p*32, i0 = (tid&7)*8;
        uint4 kr = *(const uint4*)(Kg + (size_t)t*512 + i0);
        uint4 vr = *(const uint4*)(Vg + (size_t)t*512 + i0);
        const __bf16* kp = (const __bf16*)&kr;
        const unsigned short* vp = (const unsigned short*)&vr;
        float sp = ssp[t];
        __bf16* kh = (t<32) ? sKT : sKT+2048;
        __bf16* vh = (t<32) ? sVT : sVT+2048;
#pragma unroll
        for(int j=0;j<8;j++){
            kh[(i0+j)*32 + (t&31)] = kp[j];
            vh[(i0+j)*32 + (t&31)] = f2bf(bf2f(vp[j])*sp);
        }
    }
    __syncthreads();
    f32x4 am[4] = {};
    mfma_tile(sVT, sVT+2048, sKT, sKT+2048, wave, lane, am);  // C[i][j]
    __bf16* Mo = MS + (size_t)bid*4096;
    int r0 = (wave<<4) + ((lane>>4)<<2);
#pragma unroll
    for(int nt=0;nt<4;nt++){
        int j = nt*16 + (lane&15);
#pragma unroll
        for(int r=0;r<4;r++) Mo[(size_t)(r0+r)*64 + j] = f2bf(am[nt][r]);
    }
}

// ---------------- scan C: in-reg prefix + attn (+carry_out, +rs2) -----------
__global__ __launch_bounds__(256) void scanC_k(const __bf16* __restrict__ Qb,
        const __bf16* __restrict__ Kb, const __bf16* __restrict__ Vb,
        const float* __restrict__ mask, const __bf16* __restrict__ MS,
        const float* __restrict__ carry, const float* __restrict__ Pws,
        float* __restrict__ carry_out, __bf16* __restrict__ attn,
        float* __restrict__ rs2acc){
    int bid = blockIdx.x;
    int c = bid&7, h = (bid>>3)&7, b = bid>>6;
    int bh = b*H_ + h;
    __shared__ __bf16 sQ[4096], sK[4096], sS[4096], sVT[4096], sW[4096];
    __shared__ float Wtab[64][64];
    __shared__ float scv[64], pp[64];
    int tid = threadIdx.x, wave = tid>>6, lane = tid&63;
    const __bf16* Qg = Qb + (size_t)(b*512 + c*64)*512 + h*64;
    const __bf16* Kg = Kb + (size_t)(b*512 + c*64)*512 + h*64;
    const __bf16* Vg = Vb + (size_t)(b*512 + c*64)*512 + h*64;

    stageB1(Qg, 0, 512, 0, sQ, sQ+2048, wave, lane);
    stageB1(Kg, 0, 512, 0, sK, sK+2048, wave, lane);
    if(tid<64) scv[tid] = 1.f - mask[b*512 + c*64 + tid];
#pragma unroll
    for(int p=0;p<2;p++){
        int u = (tid>>3) + p*32, i0 = (tid&7)*8;
        uint4 vr = *(const uint4*)(Vg + (size_t)u*512 + i0);
        const __bf16* vp = (const __bf16*)&vr;
        __bf16* vh = (u<32) ? sVT : sVT+2048;
#pragma unroll
        for(int j=0;j<8;j++) vh[(i0+j)*32 + (u&31)] = vp[j];
    }
    {
        int i = tid>>2, j0 = (tid&3)*16;
        float s[16];
        const float4* c4 = (const float4*)(carry + (size_t)bh*4096 + i*64 + j0);
        float4 s4[4] = {c4[0],c4[1],c4[2],c4[3]};
        float* sp = (float*)s4;
#pragma unroll
        for(int j=0;j<16;j++) s[j]=sp[j];
        for(int cc=0; cc<c; ++cc){
            float P = Pws[bh*8+cc];
            const __bf16* mp = MS + ((size_t)bh*8+cc)*4096 + i*64 + j0;
            float mv[16]; bf8_f32(*(const uint4*)mp, mv); bf8_f32(*(const uint4*)(mp+8), mv+8);
#pragma unroll
            for(int j=0;j<16;j++) s[j] = s[j]*P + mv[j];
        }
        bf16x8 w0, w1;
#pragma unroll
        for(int j=0;j<8;j++){ w0[j]=f2bf(s[j]); w1[j]=f2bf(s[8+j]); }
        __bf16* d = (j0<32) ? (sS + i*32 + j0) : (sS+2048 + i*32 + j0-32);
        *(bf16x8*)d = w0; *(bf16x8*)(d+8) = w1;
        if(c==7){
            float P = Pws[bh*8+7];
            const __bf16* mp = MS + ((size_t)bh*8+7)*4096 + i*64 + j0;
            float mv[16]; bf8_f32(*(const uint4*)mp, mv); bf8_f32(*(const uint4*)(mp+8), mv+8);
            float4 o4[4];
            float* ov = (float*)o4;
#pragma unroll
            for(int j=0;j<16;j++) ov[j] = s[j]*P + mv[j];
            float4* co = (float4*)(carry_out + (size_t)bh*4096 + i*64 + j0);
            co[0]=o4[0]; co[1]=o4[1]; co[2]=o4[2]; co[3]=o4[3];
        }
    }
    __syncthreads();
    if(tid<64){
        int u = tid; float w = 1.f;
        for(int t=0;t<64;t++){
            if(t>u) w *= scv[t];
            Wtab[u][t] = (t<u) ? 0.f : w;
        }
    }
    if(tid==64){
        float p=1.f;
        for(int t=0;t<64;t++){ p*=scv[t]; pp[t]=p; }
    }
    f32x4 sc[4] = {};
    mfma_tile(sK, sK+2048, sQ, sQ+2048, wave, lane, sc);   // C[u][t]
    __syncthreads();
    {
        int u0 = (wave<<4) + ((lane>>4)<<2);
#pragma unroll
        for(int nt=0;nt<4;nt++){
            int t = nt*16 + (lane&15);
#pragma unroll
            for(int r=0;r<4;r++){
                int u = u0 + r;
                float v = sc[nt][r] * Wtab[u][t];
                ((u<32)? sW : sW+2048)[t*32 + (u&31)] = f2bf(v);
            }
        }
    }
    __syncthreads();
    f32x4 aI[4] = {}, aX[4] = {};
    mfma_tile(sW, sW+2048, sVT, sVT+2048, wave, lane, aI); // C[t][i]
    mfma_tile(sQ, sQ+2048, sS, sS+2048, wave, lane, aX);   // C[t][i]
    int t0 = (wave<<4) + ((lane>>4)<<2);
    float attv[4][4];
    float psum[4] = {0.f,0.f,0.f,0.f};
#pragma unroll
    for(int nt=0;nt<4;nt++){
#pragma unroll
        for(int r=0;r<4;r++){
            int t = t0 + r;
            float o = aI[nt][r] + aX[nt][r]*pp[t];
            attv[nt][r] = o;
            psum[r] += o*o;
        }
    }
    rowsq_atomic(rs2acc, b*512 + c*64 + t0, lane, psum);
    __syncthreads();
    __bf16* tile = sW;
#pragma unroll
    for(int nt=0;nt<4;nt++){
        int i = nt*16 + (lane&15);
#pragma unroll
        for(int r=0;r<4;r++) tile[(t0+r)*64 + i] = f2bf(attv[nt][r]);
    }
    __syncthreads();
#pragma unroll
    for(int p=0;p<2;p++){
        int row = (tid>>3) + p*32, c0 = (tid&7)*8;
        *(uint4*)(attn + (size_t)(b*512 + c*64 + row)*512 + h*64 + c0) =
            *(const uint4*)&tile[row*64 + c0];
    }
}

// ---------------- Wo GEMM, 32x64 tiles (256 blocks), pipelined --------------
__global__ __launch_bounds__(256) void gemm_wo_k(const __bf16* __restrict__ attn,
        const float* __restrict__ rs2acc, const float* __restrict__ aln,
        const __bf16* __restrict__ Bt, const float* __restrict__ bo,
        const float* __restrict__ skip, float* __restrict__ outx,
        __bf16* __restrict__ X1, float* __restrict__ rs3acc){
    __shared__ __bf16 sA0[2][1024], sA1[2][1024], sB0[2][2048], sB1[2][2048];
    int tid=threadIdx.x, wave=tid>>6, lane=tid&63;
    int n0 = blockIdx.x*64, m0 = blockIdx.y*32;
    int arow = tid>>3;
    float r = rsqrtf(rs2acc[m0+arow]*(1.f/(float)D_) + EPS_);
    f32x4 acc[2] = {};
    int wr = (wave&1)*16, wc = (wave>>1)*32;
    {
        AR32 a = loadA32(attn, aln, m0, 512, 0, tid);
        stageB1(Bt, n0, 512, 0, sB0[0], sB1[0], wave, lane);
        writeA32(a, r, sA0[0], sA1[0], tid);
        __syncthreads();
    }
    int cur = 0;
#pragma unroll
    for(int it=0; it<8; ++it){
        int nxt = cur^1;
        AR32 a;
        if(it<7){
            a = loadA32(attn, aln, m0, 512, (it+1)*64, tid);
            stageB1(Bt, n0, 512, (it+1)*64, sB0[nxt], sB1[nxt], wave, lane);
        }
        {
            int ar = ((wr + (lane&15))<<5) + ((lane>>4)<<3);
            bf16x8 a0 = *(const bf16x8*)(sA0[cur]+ar);
            bf16x8 a1 = *(const bf16x8*)(sA1[cur]+ar);
#pragma unroll
            for(int nt=0;nt<2;nt++){
                int br = ((wc + nt*16 + (lane&15))<<5) + ((lane>>4)<<3);
                acc[nt] = MF(a0, *(const bf16x8*)(sB0[cur]+br), acc[nt]);
                acc[nt] = MF(a1, *(const bf16x8*)(sB1[cur]+br), acc[nt]);
            }
        }
        if(it<7) writeA32(a, r, sA0[nxt], sA1[nxt], tid);
        __syncthreads();
        cur = nxt;
    }
    int r0 = wr + ((lane>>4)<<2);
    float psum[4] = {0.f,0.f,0.f,0.f};
    __bf16* tile = &sA0[0][0];    // 32x64 bf16 = 4 KB
#pragma unroll
    for(int nt=0;nt<2;nt++){
        int col = n0 + wc + nt*16 + (lane&15);
#pragma unroll
        for(int rr=0;rr<4;rr++){
            int row = m0+r0+rr;
            float v = acc[nt][rr] + bo[col] + skip[(size_t)row*512+col];
            outx[(size_t)row*512+col] = v;
            tile[(r0+rr)*64 + wc + nt*16 + (lane&15)] = f2bf(v);
            psum[rr] += v*v;
        }
    }
    rowsq_atomic(rs3acc, m0+r0, lane, psum);
    __syncthreads();
    {
        int row = tid>>3, c0 = (tid&7)*8;
        *(uint4*)(X1 + (size_t)(m0+row)*512 + n0 + c0) = *(const uint4*)&tile[row*64 + c0];
    }
}

// ---------------- FFN dual GEMM + silu(g)*u, pipelined ----------------------
__global__ __launch_bounds__(256) void gemm_dual_k(const __bf16* __restrict__ X1,
        const float* __restrict__ rs3acc, const float* __restrict__ ln2,
        const __bf16* __restrict__ Gt, const __bf16* __restrict__ Ut,
        __bf16* __restrict__ Hb){
    __shared__ __bf16 sA0[2][2048], sA1[2][2048];
    __shared__ __bf16 sG0[2][2048], sG1[2][2048], sU0[2][2048], sU1[2][2048];
    int tid=threadIdx.x, wave=tid>>6, lane=tid&63;
    int n0 = blockIdx.x*64, m0 = blockIdx.y*64;
    float r = rsqrtf(rs3acc[m0+(tid>>2)]*(1.f/(float)D_) + EPS_);
    f32x4 ag[4] = {}, au[4] = {};
    {
        ARb a = loadA_bf16(X1, ln2, m0, 512, 0, tid);
        stageB1(Gt, n0, 512, 0, sG0[0], sG1[0], wave, lane);
        stageB1(Ut, n0, 512, 0, sU0[0], sU1[0], wave, lane);
        writeA_bf16(a, r, sA0[0], sA1[0], tid);
        __syncthreads();
    }
    int cur = 0;
#pragma unroll
    for(int it=0; it<8; ++it){
        int nxt = cur^1;
        ARb a;
        if(it<7){
            a = loadA_bf16(X1, ln2, m0, 512, (it+1)*64, tid);
            stageB1(Gt, n0, 512, (it+1)*64, sG0[nxt], sG1[nxt], wave, lane);
            stageB1(Ut, n0, 512, (it+1)*64, sU0[nxt], sU1[nxt], wave, lane);
        }
        {
            int ar = (((wave<<4)+(lane&15))<<5) + ((lane>>4)<<3);
            bf16x8 a0 = *(const bf16x8*)(sA0[cur]+ar);
            bf16x8 a1 = *(const bf16x8*)(sA1[cur]+ar);
#pragma unroll
            for(int nt=0;nt<4;nt++){
                int br = (((nt<<4)+(lane&15))<<5) + ((lane>>4)<<3);
                ag[nt] = MF(a0, *(const bf16x8*)(sG0[cur]+br), ag[nt]);
                ag[nt] = MF(a1, *(const bf16x8*)(sG1[cur]+br), ag[nt]);
                au[nt] = MF(a0, *(const bf16x8*)(sU0[cur]+br), au[nt]);
                au[nt] = MF(a1, *(const bf16x8*)(sU1[cur]+br), au[nt]);
            }
        }
        if(it<7) writeA_bf16(a, r, sA0[nxt], sA1[nxt], tid);
        __syncthreads();
        cur = nxt;
    }
    int r0 = (wave<<4) + ((lane>>4)<<2);
    __bf16* tile = &sA0[0][0];
#pragma unroll
    for(int nt=0;nt<4;nt++){
        int col = nt*16 + (lane&15);
#pragma unroll
        for(int rr=0;rr<4;rr++){
            float gv = ag[nt][rr], uv = au[nt][rr];
            float hv = (gv / (1.f + __expf(-gv))) * uv;
            tile[(r0+rr)*64 + col] = f2bf(hv);
        }
    }
    __syncthreads();
#pragma unroll
    for(int p=0;p<2;p++){
        int row = (tid>>3) + p*32, c0 = (tid&7)*8;
        *(uint4*)(Hb + (size_t)(m0+row)*FFN_ + n0 + c0) = *(const uint4*)&tile[row*64 + c0];
    }
}

// ---------------- Wd GEMM, split-K=8, pipelined, atomicAdd ------------------
__global__ __launch_bounds__(256) void gemm_wd_k(const __bf16* __restrict__ Hb,
        const __bf16* __restrict__ Bt, float* __restrict__ outx){
    __shared__ __bf16 sA0[2][2048], sA1[2][2048], sB0[2][2048], sB1[2][2048];
    int tid=threadIdx.x, wave=tid>>6, lane=tid&63;
    int n0 = blockIdx.x*64, m0 = blockIdx.y*64, ks = blockIdx.z*256;
    f32x4 acc[4] = {};
    int row = (wave<<4) + (lane>>2), kq = (lane&3)<<3;
    {
        stageB1(Bt, n0, FFN_, ks, sB0[0], sB1[0], wave, lane);
        const __bf16* g = Hb + (size_t)(m0+row)*FFN_ + ks + kq;
        GLOAD16(g,      sA0[0] + (wave<<9));
        GLOAD16(g + 32, sA1[0] + (wave<<9));
        __syncthreads();
    }
    int cur = 0;
#pragma unroll
    for(int it=0; it<4; ++it){
        int nxt = cur^1;
        if(it<3){
            int kk = ks + (it+1)*64;
            stageB1(Bt, n0, FFN_, kk, sB0[nxt], sB1[nxt], wave, lane);
            const __bf16* g = Hb + (size_t)(m0+row)*FFN_ + kk + kq;
            GLOAD16(g,      sA0[nxt] + (wave<<9));
            GLOAD16(g + 32, sA1[nxt] + (wave<<9));
        }
        mfma_tile(sA0[cur],sA1[cur],sB0[cur],sB1[cur],wave,lane,acc);
        __syncthreads();
        cur = nxt;
    }
    int r0 = (wave<<4) + ((lane>>4)<<2);
#pragma unroll
    for(int nt=0;nt<4;nt++){
        int col = n0 + nt*16 + (lane&15);
#pragma unroll
        for(int rr=0;rr<4;rr++)
            atomicAdd(&outx[(size_t)(m0+r0+rr)*512 + col], acc[nt][rr]);
    }
}

// ---------------------------------------------------------------------------
extern "C" void kernel_launch(void* const* d_in, const int* in_sizes, int n_in,
                              void* d_out, int out_size, void* d_ws, size_t ws_size,
                              hipStream_t stream) {
    const float* inputs  = (const float*)d_in[0];
    const float* mask    = (const float*)d_in[1];
    const float* carry   = (const float*)d_in[2];
    const float* ln1     = (const float*)d_in[3];
    const float* Wq      = (const float*)d_in[4];
    const float* Wk      = (const float*)d_in[5];
    const float* Wv      = (const float*)d_in[6];
    const float* attn_ln = (const float*)d_in[7];
    const float* Wo      = (const float*)d_in[8];
    const float* bo      = (const float*)d_in[9];
    const float* ln2     = (const float*)d_in[10];
    const float* Wg      = (const float*)d_in[11];
    const float* Wu      = (const float*)d_in[12];
    const float* Wd      = (const float*)d_in[13];

    float* out_carry = (float*)d_out;                  // 2*8*64*64 = 65536
    float* out_x     = (float*)d_out + 65536;          // 1024*512

    __bf16* wb = (__bf16*)d_ws;
    float*  wf = (float*)d_ws;
    __bf16* WgT   = wb;             // [2048][512]
    __bf16* WuT   = wb + 1048576;   // [2048][512]
    __bf16* WdT   = wb + 2097152;   // [512][2048]
    __bf16* WqkvT = wb + 3145728;   // [1536][512]
    __bf16* WoT   = wb + 3932160;   // [512][512]
    __bf16* Qb    = wb + 4194304;   // [1024][512]; attn written in place
    __bf16* Kb    = wb + 4718592;
    __bf16* Vb    = wb + 5242880;   // later X1
    __bf16* Hb    = wb + 3145728;   // [1024][2048] over dead WqkvT/WoT/Qb/Kb
    __bf16* MS    = wb + 5767168;   // [16][8][4096]
    float*  Pws   = wf + 3145728;   // 128
    float*  rs1   = wf + 3145856;   // 1024
    float*  rs2a  = wf + 3146880;   // 1024 (sumsq accum)
    float*  rs3a  = wf + 3147904;   // 1024 (sumsq accum)

    prep_k<<<dim3(1280), dim3(256), 0, stream>>>(Wg,Wu,Wd,Wq,Wk,Wv,Wo, wb, inputs, rs1, rs2a, rs3a);
    gemm_qkv_k<<<dim3(24,16), dim3(256), 0, stream>>>(inputs, rs1, ln1, WqkvT, Qb, Kb, Vb);
    scanA_k<<<dim3(128), dim3(256), 0, stream>>>(Kb, Vb, mask, MS, Pws);
    scanC_k<<<dim3(128), dim3(256), 0, stream>>>(Qb, Kb, Vb, mask, MS, carry, Pws, out_carry, /*attn->*/Qb, rs2a);
    gemm_wo_k<<<dim3(8,32), dim3(256), 0, stream>>>(Qb, rs2a, attn_ln, WoT, bo, inputs, out_x, /*X1=*/Vb, rs3a);
    gemm_dual_k<<<dim3(32,16), dim3(256), 0, stream>>>(Vb, rs3a, ln2, WgT, WuT, Hb);
    gemm_wd_k<<<dim3(8,16,8), dim3(256), 0, stream>>>(Hb, WdT, out_x);
}

// Round 10
// 158.854 us; speedup vs baseline: 1.0345x; 1.0345x over previous
//
#include <hip/hip_runtime.h>
#include <math.h>

typedef __bf16 bf16x8 __attribute__((ext_vector_type(8)));
typedef float  f32x4  __attribute__((ext_vector_type(4)));

constexpr int B_=2, S_=512, D_=512, H_=8, HD_=64, FFN_=2048, NC_=8;
constexpr float EPS_=1e-6f;

__device__ __forceinline__ __bf16 f2bf(float f){
    union{float f;unsigned u;}x; x.f=f;
    unsigned r=(x.u+0x7fffu+((x.u>>16)&1u))>>16;
    union{unsigned short s;__bf16 b;}y; y.s=(unsigned short)r; return y.b;
}
__device__ __forceinline__ float bf2f(unsigned short s){
    union{unsigned u;float f;}x; x.u=((unsigned)s)<<16; return x.f;
}
__device__ __forceinline__ void bf8_f32(uint4 p, float* o){
    unsigned w[4]={p.x,p.y,p.z,p.w};
#pragma unroll
    for(int i=0;i<4;i++){ o[2*i]=bf2f((unsigned short)(w[i]&0xffffu)); o[2*i+1]=bf2f((unsigned short)(w[i]>>16)); }
}
__device__ __forceinline__ f32x4 MF(bf16x8 a, bf16x8 b, f32x4 c){
    return __builtin_amdgcn_mfma_f32_16x16x32_bf16(a,b,c,0,0,0);
}
#define GLOAD16(g,l) __builtin_amdgcn_global_load_lds((__attribute__((address_space(1))) const void*)(g),(__attribute__((address_space(3))) void*)(l),16,0,0)

__device__ __forceinline__ void rowsq_atomic(float* accb, int row0, int lane, float p[4]){
#pragma unroll
    for(int r=0;r<4;r++){
        float v = p[r];
        v += __shfl_xor(v, 1, 64);
        v += __shfl_xor(v, 2, 64);
        v += __shfl_xor(v, 4, 64);
        v += __shfl_xor(v, 8, 64);
        if((lane&15)==0) atomicAdd(accb + row0 + r, v);
    }
}

// ---------------- prep: weight transpose+cvt, rs1, zero accumulators --------
__global__ __launch_bounds__(256) void prep_k(const float* __restrict__ Wg,
    const float* __restrict__ Wu, const float* __restrict__ Wd,
    const float* __restrict__ Wq, const float* __restrict__ Wk,
    const float* __restrict__ Wv, const float* __restrict__ Wo,
    __bf16* __restrict__ WT, const float* __restrict__ inputs,
    float* __restrict__ rs1, float* __restrict__ rs2acc, float* __restrict__ rs3acc){
    __shared__ __bf16 s[64][72];
    int t = blockIdx.x, tid = threadIdx.x;
    if(t >= 1024){
        int row = (t-1024)*4 + (tid>>6), lane = tid&63;
        const float4* p = (const float4*)(inputs + (size_t)row*D_) + lane*2;
        float4 a=p[0], b=p[1];
        float ss = a.x*a.x+a.y*a.y+a.z*a.z+a.w*a.w + b.x*b.x+b.y*b.y+b.z*b.z+b.w*b.w;
        for(int off=32; off>0; off>>=1) ss += __shfl_down(ss, off, 64);
        if(lane==0) rs1[row] = rsqrtf(ss/(float)D_ + EPS_);
        float4 z = {0.f,0.f,0.f,0.f};
        if(t==1024) ((float4*)rs2acc)[tid] = z;
        if(t==1025) ((float4*)rs3acc)[tid] = z;
        return;
    }
    const float* src; __bf16* dst; int K,N,lt;
    if      (t<256){ src=Wg; dst=WT;          K=512;  N=2048; lt=t; }
    else if (t<512){ src=Wu; dst=WT+1048576;  K=512;  N=2048; lt=t-256; }
    else if (t<768){ src=Wd; dst=WT+2097152;  K=2048; N=512;  lt=t-512; }
    else if (t<832){ src=Wq; dst=WT+3145728;  K=512;  N=512;  lt=t-768; }
    else if (t<896){ src=Wk; dst=WT+3407872;  K=512;  N=512;  lt=t-832; }
    else if (t<960){ src=Wv; dst=WT+3670016;  K=512;  N=512;  lt=t-896; }
    else           { src=Wo; dst=WT+3932160;  K=512;  N=512;  lt=t-960; }
    int nt64 = N>>6, tk = lt/nt64, tn = lt%nt64;
    {
        int jk = tid>>2, jn0 = (tid&3)*16;
        const float* p = src + (size_t)(tk*64+jk)*N + tn*64 + jn0;
        float4 a0=((const float4*)p)[0], a1=((const float4*)p)[1],
               a2=((const float4*)p)[2], a3=((const float4*)p)[3];
        bf16x8 w0, w1;
        w0[0]=f2bf(a0.x); w0[1]=f2bf(a0.y); w0[2]=f2bf(a0.z); w0[3]=f2bf(a0.w);
        w0[4]=f2bf(a1.x); w0[5]=f2bf(a1.y); w0[6]=f2bf(a1.z); w0[7]=f2bf(a1.w);
        w1[0]=f2bf(a2.x); w1[1]=f2bf(a2.y); w1[2]=f2bf(a2.z); w1[3]=f2bf(a2.w);
        w1[4]=f2bf(a3.x); w1[5]=f2bf(a3.y); w1[6]=f2bf(a3.z); w1[7]=f2bf(a3.w);
        *(bf16x8*)&s[jk][jn0] = w0; *(bf16x8*)&s[jk][jn0+8] = w1;
    }
    __syncthreads();
    {
        int jn = tid&63, jkq = (tid>>6)*16;
        bf16x8 w0, w1;
#pragma unroll
        for(int j=0;j<8;j++){ w0[j]=s[jkq+j][jn]; w1[j]=s[jkq+8+j][jn]; }
        __bf16* q = dst + (size_t)(tn*64+jn)*K + tk*64 + jkq;
        *(bf16x8*)q = w0; *(bf16x8*)(q+8) = w1;
    }
}

// ---------------- staging helpers -------------------------------------------
// one 64x64 B tile -> LDS tile region (two [64][32] halves), via global_load_lds
__device__ __forceinline__ void stageTile(const __bf16* __restrict__ Bt, int n0, int K, int kk,
                                          __bf16* dst, int wave, int lane){
    int row = (wave<<4) + (lane>>2), kq = (lane&3)<<3;
    const __bf16* g = Bt + (size_t)(n0+row)*K + kk + kq;
    GLOAD16(g,      dst + (wave<<9));
    GLOAD16(g + 32, dst + 2048 + (wave<<9));
}
struct ARf { float4 a0,a1,a2,a3, g0,g1,g2,g3; };
__device__ __forceinline__ ARf loadA_f32(const float* __restrict__ A, const float* __restrict__ g,
                                         int m0, int K, int kk, int tid){
    int row = tid>>2, kq = (tid&3)<<4;
    const float4* p = (const float4*)(A + (size_t)(m0+row)*K + kk + kq);
    const float4* gp = (const float4*)(g + kk + kq);
    ARf o;
    o.a0=p[0]; o.a1=p[1]; o.a2=p[2]; o.a3=p[3];
    o.g0=gp[0]; o.g1=gp[1]; o.g2=gp[2]; o.g3=gp[3];
    return o;
}
__device__ __forceinline__ void writeA_f32(const ARf& o, float r, __bf16* sA, int tid){
    int row = tid>>2, kq = (tid&3)<<4;
    bf16x8 w0, w1;
    w0[0]=f2bf(o.a0.x*r*o.g0.x); w0[1]=f2bf(o.a0.y*r*o.g0.y);
    w0[2]=f2bf(o.a0.z*r*o.g0.z); w0[3]=f2bf(o.a0.w*r*o.g0.w);
    w0[4]=f2bf(o.a1.x*r*o.g1.x); w0[5]=f2bf(o.a1.y*r*o.g1.y);
    w0[6]=f2bf(o.a1.z*r*o.g1.z); w0[7]=f2bf(o.a1.w*r*o.g1.w);
    w1[0]=f2bf(o.a2.x*r*o.g2.x); w1[1]=f2bf(o.a2.y*r*o.g2.y);
    w1[2]=f2bf(o.a2.z*r*o.g2.z); w1[3]=f2bf(o.a2.w*r*o.g2.w);
    w1[4]=f2bf(o.a3.x*r*o.g3.x); w1[5]=f2bf(o.a3.y*r*o.g3.y);
    w1[6]=f2bf(o.a3.z*r*o.g3.z); w1[7]=f2bf(o.a3.w*r*o.g3.w);
    __bf16* d = (kq<32) ? (sA + row*32 + kq) : (sA + 2048 + row*32 + kq-32);
    *(bf16x8*)d = w0; *(bf16x8*)(d+8) = w1;
}
struct ARb { uint4 p0,p1; float4 g0,g1,g2,g3; };
__device__ __forceinline__ ARb loadA_bf16(const __bf16* __restrict__ A, const float* __restrict__ g,
                                          int m0, int K, int kk, int tid){
    int row = tid>>2, kq = (tid&3)<<4;
    const __bf16* p = A + (size_t)(m0+row)*K + kk + kq;
    const float4* gp = (const float4*)(g + kk + kq);
    ARb o;
    o.p0 = *(const uint4*)p; o.p1 = *(const uint4*)(p+8);
    o.g0=gp[0]; o.g1=gp[1]; o.g2=gp[2]; o.g3=gp[3];
    return o;
}
__device__ __forceinline__ void writeA_bf16(const ARb& o, float r, __bf16* sA, int tid){
    int row = tid>>2, kq = (tid&3)<<4;
    float v[16]; bf8_f32(o.p0, v); bf8_f32(o.p1, v+8);
    float gf[16] = {o.g0.x,o.g0.y,o.g0.z,o.g0.w, o.g1.x,o.g1.y,o.g1.z,o.g1.w,
                    o.g2.x,o.g2.y,o.g2.z,o.g2.w, o.g3.x,o.g3.y,o.g3.z,o.g3.w};
    bf16x8 w0, w1;
#pragma unroll
    for(int j=0;j<8;j++){ w0[j]=f2bf(v[j]*r*gf[j]); w1[j]=f2bf(v[8+j]*r*gf[8+j]); }
    __bf16* d = (kq<32) ? (sA + row*32 + kq) : (sA + 2048 + row*32 + kq-32);
    *(bf16x8*)d = w0; *(bf16x8*)(d+8) = w1;
}
__device__ __forceinline__ void mfma_tile(const __bf16* sA0, const __bf16* sA1,
        const __bf16* sB0, const __bf16* sB1, int wave, int lane, f32x4 acc[4]){
    int ar = (((wave<<4)+(lane&15))<<5) + ((lane>>4)<<3);
    bf16x8 a0 = *(const bf16x8*)(sA0+ar);
    bf16x8 a1 = *(const bf16x8*)(sA1+ar);
#pragma unroll
    for(int nt=0;nt<4;nt++){
        int br = (((nt<<4)+(lane&15))<<5) + ((lane>>4)<<3);
        acc[nt] = MF(a0, *(const bf16x8*)(sB0+br), acc[nt]);
        acc[nt] = MF(a1, *(const bf16x8*)(sB1+br), acc[nt]);
    }
}

// ---------------- QKV GEMM: full B-panel prefetch, A dbuf -------------------
__global__ __launch_bounds__(256) void gemm_qkv_k(const float* __restrict__ in,
        const float* __restrict__ rs1, const float* __restrict__ ln1,
        const __bf16* __restrict__ Bt, __bf16* __restrict__ Qb,
        __bf16* __restrict__ Kb, __bf16* __restrict__ Vb){
    __shared__ __bf16 sB[32768];   // 8 tiles x 4096 = 64 KB
    __shared__ __bf16 sA[8192];    // 2 bufs x 4096 = 16 KB
    int tid=threadIdx.x, wave=tid>>6, lane=tid&63;
    int n0 = blockIdx.x*64, m0 = blockIdx.y*64;
    float r = rs1[m0+(tid>>2)];
    f32x4 acc[4] = {};
#pragma unroll
    for(int t=0;t<8;t++) stageTile(Bt, n0, 512, t*64, sB + t*4096, wave, lane);
    {
        ARf a = loadA_f32(in, ln1, m0, 512, 0, tid);
        writeA_f32(a, r, sA, tid);
    }
    __syncthreads();               // one big drain for the whole B panel
    int cur = 0;
#pragma unroll
    for(int it=0; it<8; ++it){
        ARf a;
        if(it<7) a = loadA_f32(in, ln1, m0, 512, (it+1)*64, tid);
        const __bf16* bt = sB + it*4096;
        mfma_tile(sA + cur*4096, sA + cur*4096 + 2048, bt, bt + 2048, wave, lane, acc);
        if(it<7) writeA_f32(a, r, sA + (cur^1)*4096, tid);
        __syncthreads();           // A-dbuf only; vmcnt already consumed
        cur ^= 1;
    }
    int seg = n0>>9, nc = n0&511;
    __bf16* Out = seg==0 ? Qb : (seg==1 ? Kb : Vb);
    bool rl = seg<2;
    __bf16* tile = sA;
    int r0 = (wave<<4) + ((lane>>4)<<2);
#pragma unroll
    for(int nt=0;nt<4;nt++){
        int col = nt*16 + (lane&15);
#pragma unroll
        for(int rr=0;rr<4;rr++){
            float v = acc[nt][rr]; if(rl) v = fmaxf(v,0.f);
            tile[(r0+rr)*64 + col] = f2bf(v);
        }
    }
    __syncthreads();
#pragma unroll
    for(int p=0;p<2;p++){
        int row = (tid>>3) + p*32, c0 = (tid&7)*8;
        *(uint4*)(Out + (size_t)(m0+row)*512 + nc + c0) = *(const uint4*)&tile[row*64 + c0];
    }
}

// ---------------- scan A: M[i][j] = sum_t ssp[t] v[t][i] k[t][j] ------------
__global__ __launch_bounds__(256) void scanA_k(const __bf16* __restrict__ Kb,
        const __bf16* __restrict__ Vb, const float* __restrict__ mask,
        __bf16* __restrict__ MS, float* __restrict__ Pws){
    int bid = blockIdx.x;
    int c = bid&7, h = (bid>>3)&7, b = bid>>6;
    __shared__ __bf16 sKT[4096], sVT[4096];
    __shared__ float scv[64], ssp[64];
    int tid = threadIdx.x, wave = tid>>6, lane = tid&63;
    const __bf16* Kg = Kb + (size_t)(b*512 + c*64)*512 + h*64;
    const __bf16* Vg = Vb + (size_t)(b*512 + c*64)*512 + h*64;
    if(tid<64) scv[tid] = 1.f - mask[b*512 + c*64 + tid];
    __syncthreads();
    if(tid==0){
        float sp = 1.f;
        for(int t=63;t>=0;--t){ ssp[t]=sp; sp*=scv[t]; }
        Pws[bid] = sp;
    }
    __syncthreads();
#pragma unroll
    for(int p=0;p<2;p++){
        int t = (tid>>3) + p*32, i0 = (tid&7)*8;
        uint4 kr = *(const uint4*)(Kg + (size_t)t*512 + i0);
        uint4 vr = *(const uint4*)(Vg + (size_t)t*512 + i0);
        const __bf16* kp = (const __bf16*)&kr;
        const unsigned short* vp = (const unsigned short*)&vr;
        float sp = ssp[t];
        __bf16* kh = (t<32) ? sKT : sKT+2048;
        __bf16* vh = (t<32) ? sVT : sVT+2048;
#pragma unroll
        for(int j=0;j<8;j++){
            kh[(i0+j)*32 + (t&31)] = kp[j];
            vh[(i0+j)*32 + (t&31)] = f2bf(bf2f(vp[j])*sp);
        }
    }
    __syncthreads();
    f32x4 am[4] = {};
    mfma_tile(sVT, sVT+2048, sKT, sKT+2048, wave, lane, am);  // C[i][j]
    __bf16* Mo = MS + (size_t)bid*4096;
    int r0 = (wave<<4) + ((lane>>4)<<2);
#pragma unroll
    for(int nt=0;nt<4;nt++){
        int j = nt*16 + (lane&15);
#pragma unroll
        for(int r=0;r<4;r++) Mo[(size_t)(r0+r)*64 + j] = f2bf(am[nt][r]);
    }
}

// ---------------- scan C: in-reg prefix + attn (+carry_out, +rs2) -----------
__global__ __launch_bounds__(256) void scanC_k(const __bf16* __restrict__ Qb,
        const __bf16* __restrict__ Kb, const __bf16* __restrict__ Vb,
        const float* __restrict__ mask, const __bf16* __restrict__ MS,
        const float* __restrict__ carry, const float* __restrict__ Pws,
        float* __restrict__ carry_out, __bf16* __restrict__ attn,
        float* __restrict__ rs2acc){
    int bid = blockIdx.x;
    int c = bid&7, h = (bid>>3)&7, b = bid>>6;
    int bh = b*H_ + h;
    __shared__ __bf16 sQ[4096], sK[4096], sS[4096], sVT[4096], sW[4096];
    __shared__ float Wtab[64][64];
    __shared__ float scv[64], pp[64];
    int tid = threadIdx.x, wave = tid>>6, lane = tid&63;
    const __bf16* Qg = Qb + (size_t)(b*512 + c*64)*512 + h*64;
    const __bf16* Kg = Kb + (size_t)(b*512 + c*64)*512 + h*64;
    const __bf16* Vg = Vb + (size_t)(b*512 + c*64)*512 + h*64;

    stageTile(Qg, 0, 512, 0, sQ, wave, lane);
    stageTile(Kg, 0, 512, 0, sK, wave, lane);
    if(tid<64) scv[tid] = 1.f - mask[b*512 + c*64 + tid];
#pragma unroll
    for(int p=0;p<2;p++){
        int u = (tid>>3) + p*32, i0 = (tid&7)*8;
        uint4 vr = *(const uint4*)(Vg + (size_t)u*512 + i0);
        const __bf16* vp = (const __bf16*)&vr;
        __bf16* vh = (u<32) ? sVT : sVT+2048;
#pragma unroll
        for(int j=0;j<8;j++) vh[(i0+j)*32 + (u&31)] = vp[j];
    }
    {
        int i = tid>>2, j0 = (tid&3)*16;
        float s[16];
        const float4* c4 = (const float4*)(carry + (size_t)bh*4096 + i*64 + j0);
        float4 s4[4] = {c4[0],c4[1],c4[2],c4[3]};
        float* sp = (float*)s4;
#pragma unroll
        for(int j=0;j<16;j++) s[j]=sp[j];
        for(int cc=0; cc<c; ++cc){
            float P = Pws[bh*8+cc];
            const __bf16* mp = MS + ((size_t)bh*8+cc)*4096 + i*64 + j0;
            float mv[16]; bf8_f32(*(const uint4*)mp, mv); bf8_f32(*(const uint4*)(mp+8), mv+8);
#pragma unroll
            for(int j=0;j<16;j++) s[j] = s[j]*P + mv[j];
        }
        bf16x8 w0, w1;
#pragma unroll
        for(int j=0;j<8;j++){ w0[j]=f2bf(s[j]); w1[j]=f2bf(s[8+j]); }
        __bf16* d = (j0<32) ? (sS + i*32 + j0) : (sS+2048 + i*32 + j0-32);
        *(bf16x8*)d = w0; *(bf16x8*)(d+8) = w1;
        if(c==7){
            float P = Pws[bh*8+7];
            const __bf16* mp = MS + ((size_t)bh*8+7)*4096 + i*64 + j0;
            float mv[16]; bf8_f32(*(const uint4*)mp, mv); bf8_f32(*(const uint4*)(mp+8), mv+8);
            float4 o4[4];
            float* ov = (float*)o4;
#pragma unroll
            for(int j=0;j<16;j++) ov[j] = s[j]*P + mv[j];
            float4* co = (float4*)(carry_out + (size_t)bh*4096 + i*64 + j0);
            co[0]=o4[0]; co[1]=o4[1]; co[2]=o4[2]; co[3]=o4[3];
        }
    }
    __syncthreads();
    if(tid<64){
        int u = tid; float w = 1.f;
        for(int t=0;t<64;t++){
            if(t>u) w *= scv[t];
            Wtab[u][t] = (t<u) ? 0.f : w;
        }
    }
    if(tid==64){
        float p=1.f;
        for(int t=0;t<64;t++){ p*=scv[t]; pp[t]=p; }
    }
    f32x4 sc[4] = {};
    mfma_tile(sK, sK+2048, sQ, sQ+2048, wave, lane, sc);   // C[u][t]
    __syncthreads();
    {
        int u0 = (wave<<4) + ((lane>>4)<<2);
#pragma unroll
        for(int nt=0;nt<4;nt++){
            int t = nt*16 + (lane&15);
#pragma unroll
            for(int r=0;r<4;r++){
                int u = u0 + r;
                float v = sc[nt][r] * Wtab[u][t];
                ((u<32)? sW : sW+2048)[t*32 + (u&31)] = f2bf(v);
            }
        }
    }
    __syncthreads();
    f32x4 aI[4] = {}, aX[4] = {};
    mfma_tile(sW, sW+2048, sVT, sVT+2048, wave, lane, aI); // C[t][i]
    mfma_tile(sQ, sQ+2048, sS, sS+2048, wave, lane, aX);   // C[t][i]
    int t0 = (wave<<4) + ((lane>>4)<<2);
    float attv[4][4];
    float psum[4] = {0.f,0.f,0.f,0.f};
#pragma unroll
    for(int nt=0;nt<4;nt++){
#pragma unroll
        for(int r=0;r<4;r++){
            int t = t0 + r;
            float o = aI[nt][r] + aX[nt][r]*pp[t];
            attv[nt][r] = o;
            psum[r] += o*o;
        }
    }
    rowsq_atomic(rs2acc, b*512 + c*64 + t0, lane, psum);
    __syncthreads();
    __bf16* tile = sW;
#pragma unroll
    for(int nt=0;nt<4;nt++){
        int i = nt*16 + (lane&15);
#pragma unroll
        for(int r=0;r<4;r++) tile[(t0+r)*64 + i] = f2bf(attv[nt][r]);
    }
    __syncthreads();
#pragma unroll
    for(int p=0;p<2;p++){
        int row = (tid>>3) + p*32, c0 = (tid&7)*8;
        *(uint4*)(attn + (size_t)(b*512 + c*64 + row)*512 + h*64 + c0) =
            *(const uint4*)&tile[row*64 + c0];
    }
}

// ---------------- Wo GEMM: full B-panel prefetch, A dbuf --------------------
__global__ __launch_bounds__(256) void gemm_wo_k(const __bf16* __restrict__ attn,
        const float* __restrict__ rs2acc, const float* __restrict__ aln,
        const __bf16* __restrict__ Bt, const float* __restrict__ bo,
        const float* __restrict__ skip, float* __restrict__ outx,
        __bf16* __restrict__ X1, float* __restrict__ rs3acc){
    __shared__ __bf16 sB[32768];
    __shared__ __bf16 sA[8192];
    int tid=threadIdx.x, wave=tid>>6, lane=tid&63;
    int n0 = blockIdx.x*64, m0 = blockIdx.y*64;
    float r = rsqrtf(rs2acc[m0+(tid>>2)]*(1.f/(float)D_) + EPS_);
    f32x4 acc[4] = {};
#pragma unroll
    for(int t=0;t<8;t++) stageTile(Bt, n0, 512, t*64, sB + t*4096, wave, lane);
    {
        ARb a = loadA_bf16(attn, aln, m0, 512, 0, tid);
        writeA_bf16(a, r, sA, tid);
    }
    __syncthreads();
    int cur = 0;
#pragma unroll
    for(int it=0; it<8; ++it){
        ARb a;
        if(it<7) a = loadA_bf16(attn, aln, m0, 512, (it+1)*64, tid);
        const __bf16* bt = sB + it*4096;
        mfma_tile(sA + cur*4096, sA + cur*4096 + 2048, bt, bt + 2048, wave, lane, acc);
        if(it<7) writeA_bf16(a, r, sA + (cur^1)*4096, tid);
        __syncthreads();
        cur ^= 1;
    }
    int r0 = (wave<<4) + ((lane>>4)<<2);
    float psum[4] = {0.f,0.f,0.f,0.f};
    __bf16* tile = sA;
#pragma unroll
    for(int nt=0;nt<4;nt++){
        int col = n0 + nt*16 + (lane&15);
#pragma unroll
        for(int rr=0;rr<4;rr++){
            int row = m0+r0+rr;
            float v = acc[nt][rr] + bo[col] + skip[(size_t)row*512+col];
            outx[(size_t)row*512+col] = v;
            tile[(r0+rr)*64 + nt*16 + (lane&15)] = f2bf(v);
            psum[rr] += v*v;
        }
    }
    rowsq_atomic(rs3acc, m0+r0, lane, psum);
    __syncthreads();
#pragma unroll
    for(int p=0;p<2;p++){
        int row = (tid>>3) + p*32, c0 = (tid&7)*8;
        *(uint4*)(X1 + (size_t)(m0+row)*512 + n0 + c0) = *(const uint4*)&tile[row*64 + c0];
    }
}

// ---------------- FFN dual GEMM: half-panel prefetch G/U, A dbuf ------------
__global__ __launch_bounds__(256) void gemm_dual_k(const __bf16* __restrict__ X1,
        const float* __restrict__ rs3acc, const float* __restrict__ ln2,
        const __bf16* __restrict__ Gt, const __bf16* __restrict__ Ut,
        __bf16* __restrict__ Hb){
    __shared__ __bf16 sG[16384];   // 4 tiles = 32 KB
    __shared__ __bf16 sU[16384];   // 4 tiles = 32 KB
    __shared__ __bf16 sA[8192];    // 16 KB
    int tid=threadIdx.x, wave=tid>>6, lane=tid&63;
    int n0 = blockIdx.x*64, m0 = blockIdx.y*64;
    float r = rsqrtf(rs3acc[m0+(tid>>2)]*(1.f/(float)D_) + EPS_);
    f32x4 ag[4] = {}, au[4] = {};
#pragma unroll
    for(int t=0;t<4;t++){
        stageTile(Gt, n0, 512, t*64, sG + t*4096, wave, lane);
        stageTile(Ut, n0, 512, t*64, sU + t*4096, wave, lane);
    }
    {
        ARb a = loadA_bf16(X1, ln2, m0, 512, 0, tid);
        writeA_bf16(a, r, sA, tid);
    }
    __syncthreads();
    int cur = 0;
#pragma unroll
    for(int it=0; it<8; ++it){
        if(it==4){
            // regions 0..3 fully consumed (barrier at end of it=3); refill with tiles 4..7
#pragma unroll
            for(int t=0;t<4;t++){
                stageTile(Gt, n0, 512, (4+t)*64, sG + t*4096, wave, lane);
                stageTile(Ut, n0, 512, (4+t)*64, sU + t*4096, wave, lane);
            }
            __syncthreads();
        }
        ARb a;
        if(it<7) a = loadA_bf16(X1, ln2, m0, 512, (it+1)*64, tid);
        {
            const __bf16* gt = sG + (it&3)*4096;
            const __bf16* ut = sU + (it&3)*4096;
            int ar = (((wave<<4)+(lane&15))<<5) + ((lane>>4)<<3);
            const __bf16* sAc = sA + cur*4096;
            bf16x8 a0 = *(const bf16x8*)(sAc+ar);
            bf16x8 a1 = *(const bf16x8*)(sAc+2048+ar);
#pragma unroll
            for(int nt=0;nt<4;nt++){
                int br = (((nt<<4)+(lane&15))<<5) + ((lane>>4)<<3);
                ag[nt] = MF(a0, *(const bf16x8*)(gt+br), ag[nt]);
                ag[nt] = MF(a1, *(const bf16x8*)(gt+2048+br), ag[nt]);
                au[nt] = MF(a0, *(const bf16x8*)(ut+br), au[nt]);
                au[nt] = MF(a1, *(const bf16x8*)(ut+2048+br), au[nt]);
            }
        }
        if(it<7) writeA_bf16(a, r, sA + (cur^1)*4096, tid);
        __syncthreads();
        cur ^= 1;
    }
    int r0 = (wave<<4) + ((lane>>4)<<2);
    __bf16* tile = sA;
#pragma unroll
    for(int nt=0;nt<4;nt++){
        int col = nt*16 + (lane&15);
#pragma unroll
        for(int rr=0;rr<4;rr++){
            float gv = ag[nt][rr], uv = au[nt][rr];
            float hv = (gv / (1.f + __expf(-gv))) * uv;
            tile[(r0+rr)*64 + col] = f2bf(hv);
        }
    }
    __syncthreads();
#pragma unroll
    for(int p=0;p<2;p++){
        int row = (tid>>3) + p*32, c0 = (tid&7)*8;
        *(uint4*)(Hb + (size_t)(m0+row)*FFN_ + n0 + c0) = *(const uint4*)&tile[row*64 + c0];
    }
}

// ---------------- Wd GEMM: split-K=8, full A+B panels, ONE barrier ----------
__global__ __launch_bounds__(256) void gemm_wd_k(const __bf16* __restrict__ Hb,
        const __bf16* __restrict__ Bt, float* __restrict__ outx){
    __shared__ __bf16 sA[16384];   // 4 tiles = 32 KB
    __shared__ __bf16 sB[16384];   // 4 tiles = 32 KB
    int tid=threadIdx.x, wave=tid>>6, lane=tid&63;
    int n0 = blockIdx.x*64, m0 = blockIdx.y*64, ks = blockIdx.z*256;
    f32x4 acc[4] = {};
#pragma unroll
    for(int t=0;t<4;t++){
        stageTile(Bt, n0, FFN_, ks + t*64, sB + t*4096, wave, lane);
        stageTile(Hb, m0, FFN_, ks + t*64, sA + t*4096, wave, lane);
    }
    __syncthreads();               // the only barrier
#pragma unroll
    for(int t=0;t<4;t++){
        const __bf16* at = sA + t*4096;
        const __bf16* bt = sB + t*4096;
        mfma_tile(at, at+2048, bt, bt+2048, wave, lane, acc);
    }
    int r0 = (wave<<4) + ((lane>>4)<<2);
#pragma unroll
    for(int nt=0;nt<4;nt++){
        int col = n0 + nt*16 + (lane&15);
#pragma unroll
        for(int rr=0;rr<4;rr++)
            atomicAdd(&outx[(size_t)(m0+r0+rr)*512 + col], acc[nt][rr]);
    }
}

// ---------------------------------------------------------------------------
extern "C" void kernel_launch(void* const* d_in, const int* in_sizes, int n_in,
                              void* d_out, int out_size, void* d_ws, size_t ws_size,
                              hipStream_t stream) {
    const float* inputs  = (const float*)d_in[0];
    const float* mask    = (const float*)d_in[1];
    const float* carry   = (const float*)d_in[2];
    const float* ln1     = (const float*)d_in[3];
    const float* Wq      = (const float*)d_in[4];
    const float* Wk      = (const float*)d_in[5];
    const float* Wv      = (const float*)d_in[6];
    const float* attn_ln = (const float*)d_in[7];
    const float* Wo      = (const float*)d_in[8];
    const float* bo      = (const float*)d_in[9];
    const float* ln2     = (const float*)d_in[10];
    const float* Wg      = (const float*)d_in[11];
    const float* Wu      = (const float*)d_in[12];
    const float* Wd      = (const float*)d_in[13];

    float* out_carry = (float*)d_out;                  // 2*8*64*64 = 65536
    float* out_x     = (float*)d_out + 65536;          // 1024*512

    __bf16* wb = (__bf16*)d_ws;
    float*  wf = (float*)d_ws;
    __bf16* WgT   = wb;             // [2048][512]
    __bf16* WuT   = wb + 1048576;   // [2048][512]
    __bf16* WdT   = wb + 2097152;   // [512][2048]
    __bf16* WqkvT = wb + 3145728;   // [1536][512]
    __bf16* WoT   = wb + 3932160;   // [512][512]
    __bf16* Qb    = wb + 4194304;   // [1024][512]; attn written in place
    __bf16* Kb    = wb + 4718592;
    __bf16* Vb    = wb + 5242880;   // later X1
    __bf16* Hb    = wb + 3145728;   // [1024][2048] over dead WqkvT/WoT/Qb/Kb
    __bf16* MS    = wb + 5767168;   // [16][8][4096]
    float*  Pws   = wf + 3145728;   // 128
    float*  rs1   = wf + 3145856;   // 1024
    float*  rs2a  = wf + 3146880;   // 1024 (sumsq accum)
    float*  rs3a  = wf + 3147904;   // 1024 (sumsq accum)

    prep_k<<<dim3(1280), dim3(256), 0, stream>>>(Wg,Wu,Wd,Wq,Wk,Wv,Wo, wb, inputs, rs1, rs2a, rs3a);
    gemm_qkv_k<<<dim3(24,16), dim3(256), 0, stream>>>(inputs, rs1, ln1, WqkvT, Qb, Kb, Vb);
    scanA_k<<<dim3(128), dim3(256), 0, stream>>>(Kb, Vb, mask, MS, Pws);
    scanC_k<<<dim3(128), dim3(256), 0, stream>>>(Qb, Kb, Vb, mask, MS, carry, Pws, out_carry, /*attn->*/Qb, rs2a);
    gemm_wo_k<<<dim3(8,16), dim3(256), 0, stream>>>(Qb, rs2a, attn_ln, WoT, bo, inputs, out_x, /*X1=*/Vb, rs3a);
    gemm_dual_k<<<dim3(32,16), dim3(256), 0, stream>>>(Vb, rs3a, ln2, WgT, WuT, Hb);
    gemm_wd_k<<<dim3(8,16,8), dim3(256), 0, stream>>>(Hb, WdT, out_x);
}